// Round 4
// baseline (327.139 us; speedup 1.0000x reference)
//
#include <hip/hip_runtime.h>

// QPChargeNormalization v5: per batch row b (n = 8192 = 4096 iso + 4096 aniso):
//   h = u/2 = (sum(charge[b]) - q.c) / (q.q);  x = c + h*q
//
// v4 post-mortem: ideal traffic (FETCH 133 MB, WRITE 128 MB) but HBM stuck
// at 2.35 TB/s, VALUBusy 7% -> phase-lockstep: each block load-bursts,
// drains vmcnt(0), reduces across a barrier, store-bursts; co-resident
// blocks do this in phase and the memory pipe idles during every
// reduce/barrier window.
//
// v5: software-pipeline ACROSS ROWS with counted vmcnt (guide T3/T4):
//  - each block owns 8 consecutive rows; q rows staged into double-buffered
//    LDS via global_load_lds (no dest VGPRs -> allocator cannot sink them);
//    c + charge for the NEXT row prefetched into registers, pinned by the
//    "memory" clobber on the waitcnt asm (re-load across a clobber is
//    illegal, so the allocator must keep them resident).
//  - per-row wait is s_waitcnt vmcnt(9): the next row's 9 VMEM ops stay in
//    flight across the row barrier. Raw s_barrier (NOT __syncthreads) so
//    nothing drains vmcnt. HBM streams continuously while blocks reduce.
//  - wave-chunk-local layout: wave w stages and consumes only its own
//    4 KiB q-chunk, so the vmcnt wait (own-wave queue) is sufficient and
//    no barrier is needed between staging and consumption.
//  - cross-wave combine via parity-double-buffered 3-float partials: ONE
//    raw s_barrier per row, race-free (slot p written at row r was last
//    read at row r-2; barrier(r-1) separates).
// LDS: 2 x 32 KiB qbuf + 256 B partials = 65792 B -> 2 blocks/CU,
// 16 waves/CU. grid = 512 blocks, 8 rows each.

#define HALF_N 4096          // floats per row in each of the iso/aniso halves
#define BLOCK  512
#define RPB    8             // rows per block
#define QF4    2048          // f4 per full q row (8192 floats)
#define WCHUNK 256           // f4 per wave chunk (QF4 / 8 waves)
#define SHMEM  (2 * QF4 * 16 + 2 * 32 * 4)   // 65792 B

typedef float f4 __attribute__((ext_vector_type(4)));

__device__ __forceinline__ float dot4(f4 a, f4 b) {
    return a[0]*b[0] + a[1]*b[1] + a[2]*b[2] + a[3]*b[3];
}

__device__ __forceinline__ void gload_lds16(const f4* gsrc, f4* lds_dst) {
    // 16B per lane; LDS dest = wave-uniform base + lane*16 (hardware rule)
    __builtin_amdgcn_global_load_lds(
        (const __attribute__((address_space(1))) void*)gsrc,
        (__attribute__((address_space(3))) void*)lds_dst, 16, 0, 0);
}

__global__ __launch_bounds__(BLOCK, 4) void qp_charge_norm_kernel(
    const float* __restrict__ c_iso,
    const float* __restrict__ c_aniso,
    const float* __restrict__ q_iso,
    const float* __restrict__ q_aniso,
    const float* __restrict__ charge,   // [B, 256]
    float* __restrict__ out,            // [B*4096 iso][B*4096 aniso]
    int B)
{
    extern __shared__ char smem[];
    f4*    qbuf = (f4*)smem;                    // [2][QF4]
    float* part = (float*)(smem + 2 * QF4 * 16); // [2][8 waves][4]

    const int t    = threadIdx.x;
    const int w    = t >> 6;
    const int lane = t & 63;
    const bool iso = (w < 4);
    const int  wo  = iso ? w : (w - 4);          // wave index within half

    const int b0 = blockIdx.x * RPB;
    if (b0 >= B) return;
    const int rows = (B - b0 < RPB) ? (B - b0) : RPB;

    f4    ccur[4], cnxt[4];
    float chg_cur, chg_nxt;

    // ---- prologue: prefetch row 0 (9 VMEM ops per wave) ----
    {
        const int b = b0;
        const f4* qsrc = iso ? (const f4*)(q_iso   + (size_t)b * HALF_N)
                             : (const f4*)(q_aniso + (size_t)b * HALF_N);
        const f4* csrc = iso ? (const f4*)(c_iso   + (size_t)b * HALF_N)
                             : (const f4*)(c_aniso + (size_t)b * HALF_N);
#pragma unroll
        for (int j = 0; j < 4; ++j)
            gload_lds16(qsrc + wo * WCHUNK + j * 64 + lane,
                        &qbuf[0 * QF4 + w * WCHUNK + j * 64]);
#pragma unroll
        for (int j = 0; j < 4; ++j)
            ccur[j] = csrc[wo * WCHUNK + j * 64 + lane];
        chg_cur = charge[(size_t)b * 256 + (t & 255)];
    }

    for (int r = 0; r < rows; ++r) {
        const int b = b0 + r;
        const bool pf = (r + 1 < rows);

        if (pf) {
            // ---- [A] issue next row's 9 VMEM ops (4 q->LDS, 4 c->reg, chg) ----
            const int bn = b + 1;
            const f4* qsrc = iso ? (const f4*)(q_iso   + (size_t)bn * HALF_N)
                                 : (const f4*)(q_aniso + (size_t)bn * HALF_N);
            const f4* csrc = iso ? (const f4*)(c_iso   + (size_t)bn * HALF_N)
                                 : (const f4*)(c_aniso + (size_t)bn * HALF_N);
#pragma unroll
            for (int j = 0; j < 4; ++j)
                gload_lds16(qsrc + wo * WCHUNK + j * 64 + lane,
                            &qbuf[((r + 1) & 1) * QF4 + w * WCHUNK + j * 64]);
#pragma unroll
            for (int j = 0; j < 4; ++j)
                cnxt[j] = csrc[wo * WCHUNK + j * 64 + lane];
            chg_nxt = charge[(size_t)bn * 256 + (t & 255)];

            // ---- [B] counted wait: row r's 9 loads done, row r+1's 9 in flight
            asm volatile("s_waitcnt vmcnt(9)" ::: "memory");
        } else if (r > 0) {
            // last row: newer ops = previous row's 4 stores only
            asm volatile("s_waitcnt vmcnt(4)" ::: "memory");
        } else {
            asm volatile("s_waitcnt vmcnt(0)" ::: "memory");
        }
        __builtin_amdgcn_sched_barrier(0);

        // ---- [C] dots from LDS q-chunk + register c ----
        const f4* qb = &qbuf[(r & 1) * QF4 + w * WCHUNK];
        f4 qv[4];
        float qc = 0.0f, qq = 0.0f;
#pragma unroll
        for (int j = 0; j < 4; ++j) {
            qv[j] = qb[j * 64 + lane];
            qc += dot4(qv[j], ccur[j]);
            qq += dot4(qv[j], qv[j]);
        }
        float Qs = chg_cur;   // sums to 2*Q across 512 threads

        // wave-local butterfly
#pragma unroll
        for (int off = 32; off > 0; off >>= 1) {
            qc += __shfl_xor(qc, off, 64);
            qq += __shfl_xor(qq, off, 64);
            Qs += __shfl_xor(Qs, off, 64);
        }
        float* p = part + (r & 1) * 32;
        if (lane == 0) {
            p[w * 4 + 0] = qc;
            p[w * 4 + 1] = qq;
            p[w * 4 + 2] = Qs;
        }
        asm volatile("s_waitcnt lgkmcnt(0)" ::: "memory");
        __builtin_amdgcn_s_barrier();            // raw: no vmcnt drain
        asm volatile("" ::: "memory");
        __builtin_amdgcn_sched_barrier(0);

        float tqc = 0.0f, tqq = 0.0f, tQ = 0.0f;
#pragma unroll
        for (int k = 0; k < 8; ++k) {            // broadcast reads
            tqc += p[k * 4 + 0];
            tqq += p[k * 4 + 1];
            tQ  += p[k * 4 + 2];
        }
        const float h = (0.5f * tQ - tqc) / tqq; // u/2

        // ---- [D] epilogue: x = c + h*q, 4 coalesced f4 stores ----
        f4* dst = iso ? (f4*)(out + (size_t)b * HALF_N)
                      : (f4*)(out + ((size_t)B + (size_t)b) * HALF_N);
#pragma unroll
        for (int j = 0; j < 4; ++j) {
            f4 x = ccur[j] + h * qv[j];
            dst[wo * WCHUNK + j * 64 + lane] = x;
        }

        // rotate pipeline registers
        if (pf) {
#pragma unroll
            for (int j = 0; j < 4; ++j) ccur[j] = cnxt[j];
            chg_cur = chg_nxt;
        }
    }
}

extern "C" void kernel_launch(void* const* d_in, const int* in_sizes, int n_in,
                              void* d_out, int out_size, void* d_ws, size_t ws_size,
                              hipStream_t stream) {
    const float* c_iso   = (const float*)d_in[0];
    const float* c_aniso = (const float*)d_in[1];
    const float* q_iso   = (const float*)d_in[2];
    const float* q_aniso = (const float*)d_in[3];
    const float* charge  = (const float*)d_in[4];
    float* out = (float*)d_out;

    const int B = in_sizes[0] / HALF_N;   // 4096

    static bool attr_done = false;
    if (!attr_done) {
        hipFuncSetAttribute((const void*)qp_charge_norm_kernel,
                            hipFuncAttributeMaxDynamicSharedMemorySize, SHMEM);
        attr_done = true;
    }

    const int grid = (B + RPB - 1) / RPB;   // 512
    qp_charge_norm_kernel<<<grid, BLOCK, SHMEM, stream>>>(
        c_iso, c_aniso, q_iso, q_aniso, charge, out, B);
}

// Round 5
// 323.138 us; speedup vs baseline: 1.0124x; 1.0124x over previous
//
#include <hip/hip_runtime.h>

// QPChargeNormalization v6: per batch row b (n = 8192 = 4096 iso + 4096 aniso):
//   h = u/2 = (sum(charge[b]) - q.c) / (q.q);  x = c + h*q
//
// Evidence through v5: five structurally different schedules (occupancy
// 18->73%, with/without barriers, counted-vmcnt pipelining) all land at
// 114-138 us moving ~270 MB HBM at ~2.35 TB/s. The schedule is not the
// bottleneck; the HBM footprint is.
//
// Footprint model (random-replacement MALL, 268 MB): per-iteration line
// traffic = 260 MB input reads + 128 MB kernel writes + 128 MB harness
// re-poison memset = 516 MB -> predicted input hit 268/516 = 52% ->
// FETCH = 0.48*260 = 125 MB. Measured: 136 MB. The WRITE streams
// allocating in L3 are what evicts the inputs.
//
// v6 = v4 (best: one 512-thread block/row, single pass, LDS-staged q +
// c_aniso, one __syncthreads) + ONE change: epilogue stores are
// system-scope (`global_store_dwordx4 ... sc0 sc1`) so they do not
// allocate in L2/MALL. NOT `nt`: v2 measured nt stores at exactly
// +25% WRITE amplification and higher FETCH.
// Predicted: FETCH 133 MiB -> 80-100 MiB, WRITE ~128 MiB, dur ~90-100 us.

#define HALF_N 4096   // floats per row in each of the iso/aniso halves
#define BLOCK  512

typedef float f4 __attribute__((ext_vector_type(4)));

__device__ __forceinline__ float dot4(f4 a, f4 b) {
    return a[0]*b[0] + a[1]*b[1] + a[2]*b[2] + a[3]*b[3];
}

// Store that bypasses L2/MALL allocation (system-scope write-through).
__device__ __forceinline__ void store_sys(f4* dst, f4 v) {
    asm volatile("global_store_dwordx4 %0, %1, off sc0 sc1"
                 :: "v"(dst), "v"(v) : "memory");
}

__global__ __launch_bounds__(BLOCK, 6) void qp_charge_norm_kernel(
    const float* __restrict__ c_iso,
    const float* __restrict__ c_aniso,
    const float* __restrict__ q_iso,
    const float* __restrict__ q_aniso,
    const float* __restrict__ charge,   // [B, 256]
    float* __restrict__ out,            // [B*4096 iso][B*4096 aniso]
    int B)
{
    const int b    = blockIdx.x;
    const int t    = threadIdx.x;
    const int wave = t >> 6;
    const int lane = t & 63;

    // 32 KiB q (iso 0..1023, aniso 1024..2047) + 16 KiB c_aniso + partials
    __shared__ f4    q_s[2048];
    __shared__ f4    ca_s[1024];
    __shared__ float part[24];

    const f4* ci = (const f4*)(c_iso   + (size_t)b * HALF_N);
    const f4* ca = (const f4*)(c_aniso + (size_t)b * HALF_N);
    const f4* qi = (const f4*)(q_iso   + (size_t)b * HALF_N);
    const f4* qa = (const f4*)(q_aniso + (size_t)b * HALF_N);

    // ---- single streaming pass: 8 coalesced f4 loads per thread ----
    f4 ci0 = ci[t];       f4 ci1 = ci[t + 512];
    f4 qi0 = qi[t];       f4 qi1 = qi[t + 512];
    f4 ca0 = ca[t];       f4 ca1 = ca[t + 512];
    f4 qa0 = qa[t];       f4 qa1 = qa[t + 512];

    float qc = dot4(qi0, ci0) + dot4(qi1, ci1) + dot4(qa0, ca0) + dot4(qa1, ca1);
    float qq = dot4(qi0, qi0) + dot4(qi1, qi1) + dot4(qa0, qa0) + dot4(qa1, qa1);

    // charge row: 256 floats, loaded by wave 0 as one f4 per lane
    float Q = 0.0f;
    if (wave == 0) {
        f4 ch = ((const f4*)(charge + (size_t)b * 256))[lane];
        Q = ch[0] + ch[1] + ch[2] + ch[3];
    }

    // deterministic staging: q and c_aniso live in LDS for the epilogue,
    // so the register allocator has nothing to sink to global re-reads.
    q_s[t]          = qi0;
    q_s[t + 512]    = qi1;
    q_s[1024 + t]   = qa0;
    q_s[1536 + t]   = qa1;
    ca_s[t]         = ca0;
    ca_s[t + 512]   = ca1;

    // ---- wave-local butterfly, then one cross-wave combine ----
#pragma unroll
    for (int off = 32; off > 0; off >>= 1) {
        qc += __shfl_xor(qc, off, 64);
        qq += __shfl_xor(qq, off, 64);
        Q  += __shfl_xor(Q,  off, 64);
    }
    if (lane == 0) {
        part[wave * 3 + 0] = qc;
        part[wave * 3 + 1] = qq;
        part[wave * 3 + 2] = Q;
    }
    __syncthreads();   // also covers the q_s/ca_s staging writes

    float tqc = 0.0f, tqq = 0.0f, tQ = 0.0f;
#pragma unroll
    for (int w = 0; w < 8; ++w) {   // broadcast reads, conflict-free
        tqc += part[w * 3 + 0];
        tqq += part[w * 3 + 1];
        tQ  += part[w * 3 + 2];
    }
    const float h = (tQ - tqc) / tqq;   // u/2

    // ---- epilogue: zero global re-reads; system-scope stores ----
    f4* oi = (f4*)(out + (size_t)b * HALF_N);
    f4* oa = (f4*)(out + (size_t)B * HALF_N + (size_t)b * HALF_N);

    store_sys(&oi[t],       ci0           + h * q_s[t]);
    store_sys(&oi[t + 512], ci1           + h * q_s[t + 512]);
    store_sys(&oa[t],       ca_s[t]       + h * q_s[1024 + t]);
    store_sys(&oa[t + 512], ca_s[t + 512] + h * q_s[1536 + t]);
}

extern "C" void kernel_launch(void* const* d_in, const int* in_sizes, int n_in,
                              void* d_out, int out_size, void* d_ws, size_t ws_size,
                              hipStream_t stream) {
    const float* c_iso   = (const float*)d_in[0];
    const float* c_aniso = (const float*)d_in[1];
    const float* q_iso   = (const float*)d_in[2];
    const float* q_aniso = (const float*)d_in[3];
    const float* charge  = (const float*)d_in[4];
    float* out = (float*)d_out;

    const int B = in_sizes[0] / HALF_N;   // 4096

    qp_charge_norm_kernel<<<B, BLOCK, 0, stream>>>(
        c_iso, c_aniso, q_iso, q_aniso, charge, out, B);
}

// Round 6
// 302.470 us; speedup vs baseline: 1.0816x; 1.0683x over previous
//
#include <hip/hip_runtime.h>

// QPChargeNormalization v7: per batch row b (n = 8192 = 4096 iso + 4096 aniso):
//   h = u/2 = (sum(charge[b]) - q.c) / (q.q);  x = c + h*q
//
// Evidence through v6: every schedule (occupancy 18-73%, counted-vmcnt
// pipelining, sc0/sc1 stores) lands at ~114 us moving 270 MB HBM at
// 2.35 TB/s. Marginal-rate fit across rounds: v3's EXTRA 135 MB of
// fully-sequential misses cost only +24 us (~5.6 TB/s marginal), while
// the 50%-L3-hit steady state is pinned at 2.35 TB/s. Theory: with
// inputs (260 MB) thrashing a 268 MB random-replacement L3 against the
// write stream, the HBM miss stream is a RANDOM ~50% subset of lines ->
// DRAM page locality destroyed -> ~2.4 TB/s miss service. The copy
// ubench's 6.3 TB/s is a 100%-miss SEQUENTIAL stream.
//
// v7 = v4 structure + ONE change: non-temporal input loads (nt = no L3
// allocate). Every read misses every iteration, but SEQUENTIALLY, and
// the L3 is freed for the write stream. Trades +130 MB HBM traffic for
// full DRAM page locality: 395 MB @ ~5 TB/s ~ 80 us < 114 us.
// Discriminating signal: FETCH_SIZE 133 -> ~264 MiB.

#define HALF_N 4096   // floats per row in each of the iso/aniso halves
#define BLOCK  512

typedef float f4 __attribute__((ext_vector_type(4)));

__device__ __forceinline__ float dot4(f4 a, f4 b) {
    return a[0]*b[0] + a[1]*b[1] + a[2]*b[2] + a[3]*b[3];
}

__device__ __forceinline__ f4 load_nt(const f4* p) {
    return __builtin_nontemporal_load(p);
}

__global__ __launch_bounds__(BLOCK, 6) void qp_charge_norm_kernel(
    const float* __restrict__ c_iso,
    const float* __restrict__ c_aniso,
    const float* __restrict__ q_iso,
    const float* __restrict__ q_aniso,
    const float* __restrict__ charge,   // [B, 256]
    float* __restrict__ out,            // [B*4096 iso][B*4096 aniso]
    int B)
{
    const int b    = blockIdx.x;
    const int t    = threadIdx.x;
    const int wave = t >> 6;
    const int lane = t & 63;

    // 32 KiB q (iso 0..1023, aniso 1024..2047) + 16 KiB c_aniso + partials
    __shared__ f4    q_s[2048];
    __shared__ f4    ca_s[1024];
    __shared__ float part[24];

    const f4* ci = (const f4*)(c_iso   + (size_t)b * HALF_N);
    const f4* ca = (const f4*)(c_aniso + (size_t)b * HALF_N);
    const f4* qi = (const f4*)(q_iso   + (size_t)b * HALF_N);
    const f4* qa = (const f4*)(q_aniso + (size_t)b * HALF_N);

    // ---- single streaming pass: 8 coalesced non-temporal f4 loads ----
    f4 ci0 = load_nt(&ci[t]);       f4 ci1 = load_nt(&ci[t + 512]);
    f4 qi0 = load_nt(&qi[t]);       f4 qi1 = load_nt(&qi[t + 512]);
    f4 ca0 = load_nt(&ca[t]);       f4 ca1 = load_nt(&ca[t + 512]);
    f4 qa0 = load_nt(&qa[t]);       f4 qa1 = load_nt(&qa[t + 512]);

    float qc = dot4(qi0, ci0) + dot4(qi1, ci1) + dot4(qa0, ca0) + dot4(qa1, ca1);
    float qq = dot4(qi0, qi0) + dot4(qi1, qi1) + dot4(qa0, qa0) + dot4(qa1, qa1);

    // charge row: 256 floats, loaded by wave 0 as one f4 per lane
    float Q = 0.0f;
    if (wave == 0) {
        f4 ch = load_nt(&((const f4*)(charge + (size_t)b * 256))[lane]);
        Q = ch[0] + ch[1] + ch[2] + ch[3];
    }

    // deterministic staging: q and c_aniso live in LDS for the epilogue,
    // so the register allocator has nothing to sink to global re-reads.
    q_s[t]          = qi0;
    q_s[t + 512]    = qi1;
    q_s[1024 + t]   = qa0;
    q_s[1536 + t]   = qa1;
    ca_s[t]         = ca0;
    ca_s[t + 512]   = ca1;

    // ---- wave-local butterfly, then one cross-wave combine ----
#pragma unroll
    for (int off = 32; off > 0; off >>= 1) {
        qc += __shfl_xor(qc, off, 64);
        qq += __shfl_xor(qq, off, 64);
        Q  += __shfl_xor(Q,  off, 64);
    }
    if (lane == 0) {
        part[wave * 3 + 0] = qc;
        part[wave * 3 + 1] = qq;
        part[wave * 3 + 2] = Q;
    }
    __syncthreads();   // also covers the q_s/ca_s staging writes

    float tqc = 0.0f, tqq = 0.0f, tQ = 0.0f;
#pragma unroll
    for (int w = 0; w < 8; ++w) {   // broadcast reads, conflict-free
        tqc += part[w * 3 + 0];
        tqq += part[w * 3 + 1];
        tQ  += part[w * 3 + 2];
    }
    const float h = (tQ - tqc) / tqq;   // u/2

    // ---- epilogue: zero global re-reads; plain coalesced stores ----
    f4* oi = (f4*)(out + (size_t)b * HALF_N);
    f4* oa = (f4*)(out + (size_t)B * HALF_N + (size_t)b * HALF_N);

    oi[t]       = ci0           + h * q_s[t];
    oi[t + 512] = ci1           + h * q_s[t + 512];
    oa[t]       = ca_s[t]       + h * q_s[1024 + t];
    oa[t + 512] = ca_s[t + 512] + h * q_s[1536 + t];
}

extern "C" void kernel_launch(void* const* d_in, const int* in_sizes, int n_in,
                              void* d_out, int out_size, void* d_ws, size_t ws_size,
                              hipStream_t stream) {
    const float* c_iso   = (const float*)d_in[0];
    const float* c_aniso = (const float*)d_in[1];
    const float* q_iso   = (const float*)d_in[2];
    const float* q_aniso = (const float*)d_in[3];
    const float* charge  = (const float*)d_in[4];
    float* out = (float*)d_out;

    const int B = in_sizes[0] / HALF_N;   // 4096

    qp_charge_norm_kernel<<<B, BLOCK, 0, stream>>>(
        c_iso, c_aniso, q_iso, q_aniso, charge, out, B);
}